// Round 7
// baseline (143.761 us; speedup 1.0000x reference)
//
#include <hip/hip_runtime.h>
#include <math.h>

#define NQ 14
#define NL 4
#define NS (1 << NQ)      // 16384 amplitudes
#define NT 1024           // threads per block
#define APT (NS / NT)     // 16 amps per thread

struct c32 { float x, y; };
__device__ __forceinline__ c32 cmul(c32 a, c32 b) { return {a.x*b.x - a.y*b.y, a.x*b.y + a.y*b.x}; }
__device__ __forceinline__ c32 cadd(c32 a, c32 b) { return {a.x + b.x, a.y + b.y}; }

// Physical location of logical amp y during layer L: P_L = S^L where
// S(y) = y ^ (y>>1) is the entangle gather-source map (verified r1-r6).
// S^2 = y^(y>>2), S^4 = y^(y>>4). Entangle permutation is never
// materialized; its phase is folded into the next layer's first sweep.
template<int L> __device__ __forceinline__ int permP(int y) {
    if constexpr (L == 0) return y;
    else if constexpr (L == 1) return y ^ (y >> 1);
    else if constexpr (L == 2) return y ^ (y >> 2);
    else if constexpr (L == 3) { int t = y ^ (y >> 1); return t ^ (t >> 2); }
    else return y ^ (y >> 4);   // L == 4: epilogue
}

__device__ __forceinline__ void gate8(c32* v, const float* U, const int s) {
    c32 u00={U[0],U[1]}, u01={U[2],U[3]}, u10={U[4],U[5]}, u11={U[6],U[7]};
    #pragma unroll
    for (int k = 0; k < 8; ++k) {
        if (k & s) continue;
        c32 A = v[k], B = v[k | s];
        v[k]     = cadd(cmul(u00, A), cmul(u01, B));
        v[k | s] = cadd(cmul(u10, A), cmul(u11, B));
    }
}

// Role-swapped variant for the own-amps sweep: register slot k holds the
// logical element k^t4, so a gate on bit p uses U'[i][j] = U[i^sw][j^sw],
// sw = (t4>>p)&1 (round-6-verified pattern).
__device__ __forceinline__ void gate8sw(c32* v, const float* U, const int s, const int sw) {
    c32 u00 = sw ? c32{U[6],U[7]} : c32{U[0],U[1]};
    c32 u01 = sw ? c32{U[4],U[5]} : c32{U[2],U[3]};
    c32 u10 = sw ? c32{U[2],U[3]} : c32{U[4],U[5]};
    c32 u11 = sw ? c32{U[0],U[1]} : c32{U[6],U[7]};
    #pragma unroll
    for (int k = 0; k < 8; ++k) {
        if (k & s) continue;
        c32 A = v[k], B = v[k | s];
        v[k]     = cadd(cmul(u00, A), cmul(u01, B));
        v[k | s] = cadd(cmul(u10, A), cmul(u11, B));
    }
}

// 3-qubit shared sweep on logical bit positions PB+2, PB+1, PB.
// U2 acts on bit PB+2, U1 on PB+1, U0 on PB. If FUSE, each read is
// multiplied by the previous layer's entangle phase (function of logical y).
template<int L, int PB, bool FUSE>
__device__ __forceinline__ void sweep3(float2* st,
                                       const float* U2, const float* U1, const float* U0,
                                       const float* phlo, const float* phhi, int tid) {
    #pragma unroll 1
    for (int m = 0; m < 2; ++m) {
        const int t  = tid + m*NT;
        const int ib = ((t >> PB) << (PB+3)) | (t & ((1 << PB) - 1));
        c32 v[8]; int ad[8];
        #pragma unroll
        for (int k = 0; k < 8; ++k) {
            int y = ib + (k << PB);
            int a = permP<L>(y);
            ad[k] = a;
            float2 f = st[a];
            c32 vv = {f.x, f.y};
            if constexpr (FUSE) {
                float ang = phlo[y & 127] + phhi[(y >> 7) & 63];
                float sn, cs;
                __sincosf(ang, &sn, &cs);
                vv = { cs*vv.x - sn*vv.y, cs*vv.y + sn*vv.x };
            }
            v[k] = vv;
        }
        gate8(v, U2, 4);
        gate8(v, U1, 2);
        gate8(v, U0, 1);
        #pragma unroll
        for (int k = 0; k < 8; ++k) st[ad[k]] = make_float2(v[k].x, v[k].y);
    }
}

// 2-qubit shared sweep on bits 4 (U4 = qubit 9) and 3 (U3 = qubit 10).
template<int L>
__device__ __forceinline__ void sweep2_43(float2* st, const float* U4, const float* U3, int tid) {
    #pragma unroll 1
    for (int m = 0; m < 4; ++m) {
        const int t  = tid + m*NT;
        const int ib = ((t >> 3) << 5) | (t & 7);
        c32 v[4]; int ad[4];
        #pragma unroll
        for (int k = 0; k < 4; ++k) {                // k bit0 <-> y bit3, k bit1 <-> y bit4
            int y = ib + ((k & 1) << 3) + ((k >> 1) << 4);
            int a = permP<L>(y);
            ad[k] = a;
            float2 f = st[a];
            v[k] = {f.x, f.y};
        }
        {   // qubit 9 across bit 4: pairs (k, k|2)
            c32 u00={U4[0],U4[1]}, u01={U4[2],U4[3]}, u10={U4[4],U4[5]}, u11={U4[6],U4[7]};
            #pragma unroll
            for (int k = 0; k < 4; ++k) {
                if (k & 2) continue;
                c32 A = v[k], B = v[k|2];
                v[k]   = cadd(cmul(u00,A), cmul(u01,B));
                v[k|2] = cadd(cmul(u10,A), cmul(u11,B));
            }
        }
        {   // qubit 10 across bit 3: pairs (k, k|1)
            c32 u00={U3[0],U3[1]}, u01={U3[2],U3[3]}, u10={U3[4],U3[5]}, u11={U3[6],U3[7]};
            #pragma unroll
            for (int k = 0; k < 4; ++k) {
                if (k & 1) continue;
                c32 A = v[k], B = v[k|1];
                v[k]   = cadd(cmul(u00,A), cmul(u01,B));
                v[k|1] = cadd(cmul(u10,A), cmul(u11,B));
            }
        }
        #pragma unroll
        for (int k = 0; k < 4; ++k) st[ad[k]] = make_float2(v[k].x, v[k].y);
    }
}

// Own-amps sweep: qubits 11,12,13 (bits 2,1,0) on the thread's 16 logical
// amps (base = tid<<4). Slot s in tuple m holds logical e = (m*8+s)^t4
// (bank-spread order); gates use role-swapped matrices. No barriers inside.
template<int L>
__device__ __forceinline__ void sweep_own(float2* st,
                                          const float* U11, const float* U12, const float* U13,
                                          int tid) {
    const int t4   = tid & 15;
    const int base = tid << 4;
    #pragma unroll 1
    for (int m = 0; m < 2; ++m) {
        c32 v[8]; int ad[8];
        #pragma unroll
        for (int s = 0; s < 8; ++s) {
            int e = ((m << 3) | s) ^ t4;
            int a = permP<L>(base | e);
            ad[s] = a;
            float2 f = st[a];
            v[s] = {f.x, f.y};
        }
        gate8sw(v, U11, 4, (t4 >> 2) & 1);
        gate8sw(v, U12, 2, (t4 >> 1) & 1);
        gate8sw(v, U13, 1,  t4       & 1);
        #pragma unroll
        for (int s = 0; s < 8; ++s) st[ad[s]] = make_float2(v[s].x, v[s].y);
    }
}

template<int L>
__device__ __forceinline__ void do_layer(float2* st, float (*UmL)[8],
                                         const float* phlo, const float* phhi, int tid) {
    constexpr bool F = (L > 0);
    sweep3<L, 11, F>(st, UmL[0], UmL[1], UmL[2], phlo, phhi, tid);   // qubits 0,1,2 (+ prev entangle)
    __syncthreads();
    sweep3<L, 8, false>(st, UmL[3], UmL[4], UmL[5], nullptr, nullptr, tid);  // qubits 3,4,5
    __syncthreads();
    sweep3<L, 5, false>(st, UmL[6], UmL[7], UmL[8], nullptr, nullptr, tid);  // qubits 6,7,8
    __syncthreads();
    sweep2_43<L>(st, UmL[9], UmL[10], tid);                           // qubits 9,10
    __syncthreads();
    sweep_own<L>(st, UmL[11], UmL[12], UmL[13], tid);                 // qubits 11,12,13
    __syncthreads();
}

__global__ __launch_bounds__(NT) __attribute__((amdgpu_waves_per_eu(4, 4)))
void qc_kernel(const float* __restrict__ x,
               const float* __restrict__ prx,
               const float* __restrict__ pry,
               const float* __restrict__ prz,
               const float* __restrict__ pent,
               float* __restrict__ out)
{
    __shared__ float2 st[NS];            // 128 KB state
    __shared__ float  Um[NL][NQ][8];     // fused RZ*RY*RX 2x2 complex per (layer,qubit)
    __shared__ float  tlo[NL][128];      // entangle phase table, bit positions 0..6
    __shared__ float  thi[NL][64];       // bit positions 7..12
    __shared__ float  encc[NQ], encs[NQ];
    __shared__ float  red[NT/64][NQ];

    const int tid = threadIdx.x;
    const int b   = blockIdx.x;

    // ---------------- precompute (one barrier) ----------------
    if (tid < NL*NQ) {
        int l = tid / NQ, q = tid % NQ;
        float hx = 0.5f*prx[l*NQ+q], hy = 0.5f*pry[l*NQ+q], hz = 0.5f*prz[l*NQ+q];
        float cx = cosf(hx), sx = sinf(hx);
        float cy = cosf(hy), sy = sinf(hy);
        float cz = cosf(hz), sz = sinf(hz);
        // M = Ry*Rx
        c32 m00 = { cy*cx,  sy*sx };
        c32 m01 = {-sy*cx, -cy*sx };
        c32 m10 = { sy*cx, -cy*sx };
        c32 m11 = { cy*cx, -sy*sx };
        // U = Rz*M : row0 *= e^{-i hz}, row1 *= e^{+i hz}
        c32 e0 = {cz, -sz}, e1 = {cz, sz};
        c32 u00 = cmul(e0, m00), u01 = cmul(e0, m01);
        c32 u10 = cmul(e1, m10), u11 = cmul(e1, m11);
        float* U = Um[l][q];
        U[0]=u00.x; U[1]=u00.y; U[2]=u01.x; U[3]=u01.y;
        U[4]=u10.x; U[5]=u10.y; U[6]=u11.x; U[7]=u11.y;
    } else if (tid >= 64 && tid < 64 + NL*192) {
        int t2 = tid - 64;
        int l = t2 / 192, r = t2 % 192;
        if (r < 128) {                       // positions p=0..6, theta index 12-p
            float a = 0.f;
            for (int p = 0; p < 7; ++p) {
                float th = 0.5f * pent[l*(NQ-1) + (12 - p)];
                a += ((r >> p) & 1) ? th : -th;
            }
            tlo[l][r] = a;
        } else {                             // positions p=7..12, theta index 5-p'
            int m = r - 128;
            float a = 0.f;
            for (int p = 0; p < 6; ++p) {
                float th = 0.5f * pent[l*(NQ-1) + (5 - p)];
                a += ((m >> p) & 1) ? th : -th;
            }
            thi[l][m] = a;
        }
    } else if (tid >= 960 && tid < 960 + NQ) {
        int i = tid - 960;
        float th = tanhf(x[b*NQ + i]) * 3.14159265358979323846f;
        encc[i] = cosf(0.5f*th);
        encs[i] = sinf(0.5f*th);
    }
    __syncthreads();

    // ---------------- init: product state from RY encoding ----------------
    {
        float prodLow = 1.f;
        #pragma unroll
        for (int p = 0; p < 10; ++p) {       // idx bits 0..9 come from tid; qubit = 13-p
            prodLow *= ((tid >> p) & 1) ? encs[13-p] : encc[13-p];
        }
        #pragma unroll
        for (int j = 0; j < APT; ++j) {      // idx bits 10..13 come from j; qubit = 3..0
            float a = prodLow;
            a *= (j & 1) ? encs[3] : encc[3];
            a *= (j & 2) ? encs[2] : encc[2];
            a *= (j & 4) ? encs[1] : encc[1];
            a *= (j & 8) ? encs[0] : encc[0];
            st[tid + j*NT] = make_float2(a, 0.f);
        }
    }
    __syncthreads();

    // ---------------- 4 layers: 5 sweeps each, entangle fused into reads ----
    do_layer<0>(st, Um[0], nullptr, nullptr, tid);
    do_layer<1>(st, Um[1], tlo[0], thi[0], tid);
    do_layer<2>(st, Um[2], tlo[1], thi[1], tid);
    do_layer<3>(st, Um[3], tlo[2], thi[2], tid);

    // ---------------- epilogue: entangle-3 (perm+phase) fused with <Z_i> ----
    float acc[NQ];
    #pragma unroll
    for (int i = 0; i < NQ; ++i) acc[i] = 0.f;
    #pragma unroll
    for (int j = 0; j < APT; ++j) {
        int y = tid + j*NT;
        int a = permP<4>(y);                 // P_3(S(y)) = S^4(y) = y ^ (y>>4)
        float2 v = st[a];
        float ang = tlo[NL-1][y & 127] + thi[NL-1][(y >> 7) & 63];
        float sn, cs;
        __sincosf(ang, &sn, &cs);
        float re = cs*v.x - sn*v.y;
        float im = cs*v.y + sn*v.x;
        float pr = re*re + im*im;
        #pragma unroll
        for (int p = 0; p < NQ; ++p) {       // qubit NQ-1-p at bit position p
            acc[NQ-1-p] += ((y >> p) & 1) ? -pr : pr;
        }
    }
    #pragma unroll
    for (int off = 32; off >= 1; off >>= 1) {
        #pragma unroll
        for (int i = 0; i < NQ; ++i)
            acc[i] += __shfl_down(acc[i], off, 64);
    }
    const int wid = tid >> 6, lane = tid & 63;
    if (lane == 0) {
        #pragma unroll
        for (int i = 0; i < NQ; ++i) red[wid][i] = acc[i];
    }
    __syncthreads();
    if (tid < NQ) {
        float s = 0.f;
        #pragma unroll
        for (int w = 0; w < NT/64; ++w) s += red[w][tid];
        out[b*NQ + tid] = s;
    }
}

extern "C" void kernel_launch(void* const* d_in, const int* in_sizes, int n_in,
                              void* d_out, int out_size, void* d_ws, size_t ws_size,
                              hipStream_t stream) {
    (void)d_ws; (void)ws_size; (void)n_in; (void)out_size;
    const float* x    = (const float*)d_in[0];
    const float* prx  = (const float*)d_in[1];
    const float* pry  = (const float*)d_in[2];
    const float* prz  = (const float*)d_in[3];
    const float* pent = (const float*)d_in[4];
    float* out = (float*)d_out;
    const int B = in_sizes[0] / NQ;
    qc_kernel<<<B, NT, 0, stream>>>(x, prx, pry, prz, pent, out);
}